// Round 9
// baseline (548.961 us; speedup 1.0000x reference)
//
#include <hip/hip_runtime.h>

// SlotAttention fused implementation (bf16 hln, row-major).
//   - 6-layer linear stack folded into effective 66->128 affine (Wh, bh).
//   - k,v projections folded out of the N dimension:
//       q.k_n = (wk@q) . hln_n + q.bk ;  updates = (sum attn*hln)/den @ wv + bv
//   - hln = LN(h) materialized BF16 row-major [NB][128]  (64 MB, L3-resident).
//   - slot init: JAX partitionable threefry: bits[i] = o0^o1, counter (0,i).
//   - k4 v3: fully register-resident. Row r = 16k+(t>>4) lives in the 16
//     consecutive lanes c8=t&15; dots reduced via shfl_xor(1,2,4,8); softmax
//     + vec-accumulation in regs; no LDS tile, no per-tile barriers.

#define B_  8
#define N_  32768
#define NB_ (B_ * N_)   // 262144 rows
#define D_  128
#define S_  8

typedef unsigned int u32;

__device__ inline u32 bfr1(float x) {  // f32 -> bf16 (RNE)
    u32 u = __float_as_uint(x);
    return (u + 0x7FFFu + ((u >> 16) & 1u)) >> 16;
}
__device__ inline u32 bfpack(float lo, float hi) { return bfr1(lo) | (bfr1(hi) << 16); }

// threefry2x32, key = (0, 42)  (jax.random.key(42))
__device__ inline void threefry42(u32 c0, u32 c1, u32& o0, u32& o1) {
    const u32 k0 = 0u, k1 = 42u, k2 = 0x1BD11BDAu ^ 0u ^ 42u;
    const u32 ks[3] = {k0, k1, k2};
    u32 x0 = c0 + k0, x1 = c1 + k1;
    const int rA[4] = {13, 15, 26, 6}, rB[4] = {17, 29, 16, 24};
#pragma unroll
    for (int i = 0; i < 5; i++) {
#pragma unroll
        for (int k = 0; k < 4; k++) {
            int r = (i & 1) ? rB[k] : rA[k];
            x0 += x1;
            x1 = (x1 << r) | (x1 >> (32 - r));
            x1 ^= x0;
        }
        x0 += ks[(i + 1) % 3];
        x1 += ks[(i + 2) % 3] + (u32)(i + 1);
    }
    o0 = x0; o1 = x1;
}

// jax uniform(-0.99999994, 1) -> sqrt(2)*erfinv  (XLA ErfInv32 polynomial)
__device__ inline float bits_to_normal(u32 b) {
    float f = __uint_as_float((b >> 9) | 0x3f800000u) - 1.0f;  // [0,1)
    const float lo = -0.99999994f;
    float r = fmaxf(lo, f * 1.99999994f + lo);
    float w = -log1pf(-r * r);
    float p;
    if (w < 5.0f) {
        w -= 2.5f;
        p = 2.81022636e-08f;
        p = fmaf(p, w, 3.43273939e-07f);
        p = fmaf(p, w, -3.5233877e-06f);
        p = fmaf(p, w, -4.39150654e-06f);
        p = fmaf(p, w, 0.00021858087f);
        p = fmaf(p, w, -0.00125372503f);
        p = fmaf(p, w, -0.00417768164f);
        p = fmaf(p, w, 0.246640727f);
        p = fmaf(p, w, 1.50140941f);
    } else {
        w = sqrtf(w) - 3.0f;
        p = -0.000200214257f;
        p = fmaf(p, w, 0.000100950558f);
        p = fmaf(p, w, 0.00134934322f);
        p = fmaf(p, w, -0.00367342844f);
        p = fmaf(p, w, 0.00573950773f);
        p = fmaf(p, w, -0.0076224613f);
        p = fmaf(p, w, 0.00943887047f);
        p = fmaf(p, w, 1.00167406f);
        p = fmaf(p, w, 2.83297682f);
    }
    return 1.41421356f * (p * r);
}

// 128-thread block sum (2 waves), red = 2-float shared scratch
__device__ inline float block128_sum(float v, float* red) {
#pragma unroll
    for (int o = 32; o; o >>= 1) v += __shfl_down(v, o);
    __syncthreads();
    if ((threadIdx.x & 63) == 0) red[threadIdx.x >> 6] = v;
    __syncthreads();
    return red[0] + red[1];
}

// LN(slot row) -> q -> qtilde(scaled), qc(scaled); zero vec/den accumulators.
__device__ void emit_q(float x, int bs,
                       const float* lnsg, const float* lnsb,
                       const float* wq, const float* bq,
                       const float* wkT, const float* bk,
                       float* qt, float* qc, float* vec, float* den,
                       float* shA, float* red) {
    int t = threadIdx.x;
    float m = block128_sum(x, red) * (1.0f / 128.0f);
    float e = x - m;
    float var = block128_sum(e * e, red) * (1.0f / 128.0f);
    float inv = rsqrtf(var + 1e-5f);
    __syncthreads();
    shA[t] = fmaf(e * inv, lnsg[t], lnsb[t]);
    __syncthreads();
    float q = bq[t];
#pragma unroll 4
    for (int i = 0; i < 128; i++) q = fmaf(shA[i], wq[i * 128 + t], q);
    __syncthreads();
    shA[t] = q;
    __syncthreads();
    float a2 = 0.f;
#pragma unroll 4
    for (int j = 0; j < 128; j++) a2 = fmaf(wkT[j * 128 + t], shA[j], a2);
    const float scale = 0.08838834764831845f;  // 128^-0.5
    qt[bs * 128 + t] = a2 * scale;
    float pr = block128_sum(shA[t] * bk[t], red);
    if (t == 0) { qc[bs] = pr * scale; den[bs] = 0.f; }
    vec[bs * 128 + t] = 0.f;
}

// ---------- K0: transpose gru weights + wk for coalesced access ----------

__global__ __launch_bounds__(256) void k0_transpose(
    const float* __restrict__ wih, const float* __restrict__ whh,
    const float* __restrict__ wk,
    float* __restrict__ wihT, float* __restrict__ whhT, float* __restrict__ wkT) {
    int idx = blockIdx.x * 256 + threadIdx.x;
    if (idx < 49152) {
        int d = idx / 384, g = idx % 384;
        wihT[idx] = wih[g * 128 + d];
    } else if (idx < 98304) {
        int o = idx - 49152;
        int d = o / 384, g = o % 384;
        whhT[o] = whh[g * 128 + d];
    } else if (idx < 114688) {
        int o = idx - 98304;
        int j = o >> 7, tcol = o & 127;
        wkT[o] = wk[tcol * 128 + j];
    }
}

// ---------- K1: fold weights, init slots ----------

__global__ __launch_bounds__(256) void k1_setup(
    const float* __restrict__ w0, const float* __restrict__ b0,
    const float* __restrict__ w1, const float* __restrict__ b1,
    const float* __restrict__ w2, const float* __restrict__ b2,
    const float* __restrict__ w3, const float* __restrict__ b3,
    const float* __restrict__ w4, const float* __restrict__ b4,
    const float* __restrict__ w5, const float* __restrict__ b5,
    const float* __restrict__ w7, const float* __restrict__ b7,
    const float* __restrict__ mu, const float* __restrict__ sg,
    float* __restrict__ Wh, float* __restrict__ bh, float* __restrict__ slots) {
    __shared__ float A[192], Bt[96], bb[64], bb2[32];
    __shared__ float stats[2];
    int t = threadIdx.x;
    for (int i = t; i < 192; i += 256) A[i] = w0[i];
    for (int i = t; i < 64; i += 256) bb[i] = b0[i];
    __syncthreads();
    const float* wl[5] = {w1, w2, w3, w4, w5};
    const float* bl[5] = {b1, b2, b3, b4, b5};
    int kin = 64;
    for (int l = 0; l < 5; l++) {
        const float* w = wl[l];
        const float* bias = bl[l];
        if (t < 96) {
            int i = t / 32, j = t % 32;
            float acc = 0.f;
            for (int k = 0; k < kin; k++) acc += A[i * kin + k] * w[k * 32 + j];
            Bt[i * 32 + j] = acc;
        } else if (t < 128) {
            int j = t - 96;
            float acc = bias[j];
            for (int k = 0; k < kin; k++) acc += bb[k] * w[k * 32 + j];
            bb2[j] = acc;
        }
        __syncthreads();
        if (t < 96) A[t] = Bt[t];
        if (t < 32) bb[t] = bb2[t];
        __syncthreads();
        kin = 32;
    }
    for (int idx = t; idx < 66 * 128; idx += 256) {
        int i = idx >> 7, j = idx & 127;
        float acc = w7[idx];
        if (i < 3) {
            for (int k = 0; k < 32; k++) acc += A[i * 32 + k] * w7[(66 + k) * 128 + j];
        }
        Wh[idx] = acc;
    }
    for (int j = t; j < 128; j += 256) {
        float acc = b7[j];
        for (int k = 0; k < 32; k++) acc += bb[k] * w7[(66 + k) * 128 + j];
        bh[j] = acc;
    }
    if (t == 0) {
        float s1 = 0.f, s2 = 0.f;
        for (int d = 0; d < 128; d++) { s1 += mu[d]; s2 += sg[d]; }
        float mmu = s1 / 128.f, msg = s2 / 128.f;
        float ss = 0.f;
        for (int d = 0; d < 128; d++) { float e = sg[d] - msg; ss += e * e; }
        stats[0] = mmu;
        stats[1] = sqrtf(64.f * ss / 8191.f);  // std over broadcast 8192, ddof=1
    }
    __syncthreads();
    float mean = stats[0], sd = stats[1];
    for (int p = t; p < 8192; p += 256) {
        u32 o0, o1;
        threefry42(0u, (u32)p, o0, o1);
        slots[p] = fmaf(sd, bits_to_normal(o0 ^ o1), mean);
    }
}

// ---------- K2: build hln (bf16 row-major [NB][128]) ----------
// 128 rows/block; thread (tr 0-15, tc 0-15): rows tr*8..+7, f4-col quads {tc, tc+16}.
// w-reads inside kk-loop (no preload arrays) to keep live regs ~110 (no spill).

__global__ __launch_bounds__(256) void k2_hln(
    const float* __restrict__ inputs, const float* __restrict__ embed,
    const float* __restrict__ Wh, const float* __restrict__ bh,
    const float* __restrict__ g, const float* __restrict__ bbias,
    uint2* __restrict__ hlnb) {
    __shared__ __align__(16) float Whs[66 * 132];   // 34848 B (stride 33 f4)
    __shared__ __align__(16) float ebuf[128 * 68];  // 34816 B (stride 17 f4)
    __shared__ __align__(16) float bhs[128], gs[128], bs_[128];
    int t = threadIdx.x;
    for (int gi = t; gi < 66 * 128; gi += 256) {
        int i = gi >> 7, d = gi & 127;
        Whs[i * 132 + d] = Wh[gi];
    }
    if (t < 128) { bhs[t] = bh[t]; gs[t] = g[t]; bs_[t] = bbias[t]; }
    size_t rbase = (size_t)blockIdx.x * 128;
    for (int idx = t; idx < 384; idx += 256)
        ebuf[(idx / 3) * 68 + (idx % 3)] = inputs[rbase * 3 + idx];
    for (int idx = t; idx < 128 * 63; idx += 256) {
        int rr = idx / 63, i = idx - rr * 63;
        ebuf[rr * 68 + 3 + i] = embed[rbase * 63 + idx];
    }
    __syncthreads();
    int tr = t >> 4, tc = t & 15;
    const float4* Whs4 = (const float4*)Whs;
    const float4* ebuf4 = (const float4*)ebuf;
    float4 acc0[8], acc1[8];
    float4 b40 = *(const float4*)&bhs[tc * 4];
    float4 b41 = *(const float4*)&bhs[64 + tc * 4];
#pragma unroll
    for (int r8 = 0; r8 < 8; r8++) { acc0[r8] = b40; acc1[r8] = b41; }
#pragma unroll 2
    for (int kc = 0; kc < 16; kc++) {
        float4 e4[8];
#pragma unroll
        for (int r8 = 0; r8 < 8; r8++) e4[r8] = ebuf4[(tr * 8 + r8) * 17 + kc];
#pragma unroll
        for (int kk = 0; kk < 4; kk++) {
            float4 w0t = Whs4[(kc * 4 + kk) * 33 + tc];
            float4 w1t = Whs4[(kc * 4 + kk) * 33 + 16 + tc];
#pragma unroll
            for (int r8 = 0; r8 < 8; r8++) {
                float e = (kk == 0) ? e4[r8].x : (kk == 1) ? e4[r8].y
                        : (kk == 2) ? e4[r8].z : e4[r8].w;
                acc0[r8].x = fmaf(e, w0t.x, acc0[r8].x);
                acc0[r8].y = fmaf(e, w0t.y, acc0[r8].y);
                acc0[r8].z = fmaf(e, w0t.z, acc0[r8].z);
                acc0[r8].w = fmaf(e, w0t.w, acc0[r8].w);
                acc1[r8].x = fmaf(e, w1t.x, acc1[r8].x);
                acc1[r8].y = fmaf(e, w1t.y, acc1[r8].y);
                acc1[r8].z = fmaf(e, w1t.z, acc1[r8].z);
                acc1[r8].w = fmaf(e, w1t.w, acc1[r8].w);
            }
        }
    }
    // tail k = 64, 65
#pragma unroll
    for (int k = 64; k < 66; k++) {
        float4 w0t = Whs4[k * 33 + tc];
        float4 w1t = Whs4[k * 33 + 16 + tc];
#pragma unroll
        for (int r8 = 0; r8 < 8; r8++) {
            float e = ebuf[(tr * 8 + r8) * 68 + k];
            acc0[r8].x = fmaf(e, w0t.x, acc0[r8].x); acc0[r8].y = fmaf(e, w0t.y, acc0[r8].y);
            acc0[r8].z = fmaf(e, w0t.z, acc0[r8].z); acc0[r8].w = fmaf(e, w0t.w, acc0[r8].w);
            acc1[r8].x = fmaf(e, w1t.x, acc1[r8].x); acc1[r8].y = fmaf(e, w1t.y, acc1[r8].y);
            acc1[r8].z = fmaf(e, w1t.z, acc1[r8].z); acc1[r8].w = fmaf(e, w1t.w, acc1[r8].w);
        }
    }
    // per-row LN across the 16 tc lanes
    float4 gg0 = *(const float4*)&gs[tc * 4];
    float4 gg1 = *(const float4*)&gs[64 + tc * 4];
    float4 bb0 = *(const float4*)&bs_[tc * 4];
    float4 bb1 = *(const float4*)&bs_[64 + tc * 4];
#pragma unroll
    for (int r8 = 0; r8 < 8; r8++) {
        float v = acc0[r8].x + acc0[r8].y + acc0[r8].z + acc0[r8].w
                + acc1[r8].x + acc1[r8].y + acc1[r8].z + acc1[r8].w;
        v += __shfl_xor(v, 1); v += __shfl_xor(v, 2);
        v += __shfl_xor(v, 4); v += __shfl_xor(v, 8);
        float m = v * (1.0f / 128.0f);
        float e0x = acc0[r8].x - m, e0y = acc0[r8].y - m, e0z = acc0[r8].z - m, e0w = acc0[r8].w - m;
        float e1x = acc1[r8].x - m, e1y = acc1[r8].y - m, e1z = acc1[r8].z - m, e1w = acc1[r8].w - m;
        float s2 = e0x * e0x + e0y * e0y + e0z * e0z + e0w * e0w
                 + e1x * e1x + e1y * e1y + e1z * e1z + e1w * e1w;
        s2 += __shfl_xor(s2, 1); s2 += __shfl_xor(s2, 2);
        s2 += __shfl_xor(s2, 4); s2 += __shfl_xor(s2, 8);
        float inv = rsqrtf(s2 * (1.0f / 128.0f) + 1e-5f);
        float f0x = fmaf(e0x * inv, gg0.x, bb0.x), f0y = fmaf(e0y * inv, gg0.y, bb0.y);
        float f0z = fmaf(e0z * inv, gg0.z, bb0.z), f0w = fmaf(e0w * inv, gg0.w, bb0.w);
        float f1x = fmaf(e1x * inv, gg1.x, bb1.x), f1y = fmaf(e1y * inv, gg1.y, bb1.y);
        float f1z = fmaf(e1z * inv, gg1.z, bb1.z), f1w = fmaf(e1w * inv, gg1.w, bb1.w);
        size_t row = rbase + tr * 8 + r8;
        uint2 o0; o0.x = bfpack(f0x, f0y); o0.y = bfpack(f0z, f0w);
        uint2 o1; o1.x = bfpack(f1x, f1y); o1.y = bfpack(f1z, f1w);
        hlnb[row * 32 + tc] = o0;
        hlnb[row * 32 + 16 + tc] = o1;
    }
}

// ---------- K3: initial q from slots ----------

__global__ __launch_bounds__(128) void k3_q(
    const float* __restrict__ slots,
    const float* __restrict__ lnsg, const float* __restrict__ lnsb,
    const float* __restrict__ wq, const float* __restrict__ bq,
    const float* __restrict__ wkT, const float* __restrict__ bk,
    float* __restrict__ qt, float* __restrict__ qc,
    float* __restrict__ vec, float* __restrict__ den) {
    __shared__ float shA[128];
    __shared__ float red[2];
    int bs = blockIdx.x;
    float x = slots[bs * 128 + threadIdx.x];
    emit_q(x, bs, lnsg, lnsb, wq, bq, wkT, bk, qt, qc, vec, den, shA, red);
}

// ---------- K4 v3: register-resident attention pass ----------
// 1024 blocks x 256 thr; block owns 256 rows = 4 tiles of 64.
// Thread: c8 = t&15 (8-dim chunk), j = t>>4; row = 16k + j per staging reg k.

__global__ __launch_bounds__(256) void k4_attn(
    const uint4* __restrict__ hlnb4, const float* __restrict__ qt,
    const float* __restrict__ qc, float* __restrict__ vec, float* __restrict__ den) {
    __shared__ __align__(16) float qx[16 * 68];       // [c8][s*8+dd], stride 68
    __shared__ __align__(16) float vlds[4 * 1088];    // [wave][c8*68 + s*8+dd]
    __shared__ float dlds[32];
    __shared__ float qcl[8];
    int t = threadIdx.x;
    int blk = blockIdx.x;
    int b = blk >> 7, slab = blk & 127;
    size_t row0 = (size_t)b * N_ + (size_t)slab * 256;
    const uint4* src = hlnb4 + row0 * 16;   // 16 uint4 (128 bf16) per row

    for (int i = t; i < 1024; i += 256) {
        int s = i >> 7, d = i & 127;
        qx[(d >> 3) * 68 + s * 8 + (d & 7)] = qt[b * 1024 + i];
    }
    if (t < 8) qcl[t] = qc[b * 8 + t];
    __syncthreads();

    int c8 = t & 15;
    const float4* qx4 = (const float4*)qx;  // per-c8 stride 17 f4
    float qcr[8];
#pragma unroll
    for (int s = 0; s < 8; s++) qcr[s] = qcl[s];

    float acc[8][8];
#pragma unroll
    for (int s = 0; s < 8; s++)
#pragma unroll
        for (int dd = 0; dd < 8; dd++) acc[s][dd] = 0.f;
    float dden[8] = {0.f, 0.f, 0.f, 0.f, 0.f, 0.f, 0.f, 0.f};

    uint4 st[4], stn[4];
#pragma unroll
    for (int k = 0; k < 4; k++) st[k] = src[t + k * 256];

    for (int tt = 0; tt < 4; tt++) {
        if (tt < 3) {
            const uint4* spn = src + (size_t)(tt + 1) * 1024;
#pragma unroll
            for (int k = 0; k < 4; k++) stn[k] = spn[t + k * 256];
        }
#pragma unroll
        for (int k = 0; k < 4; k++) {
            uint4 u = st[k];
            float hf[8];
            hf[0] = __uint_as_float(u.x << 16); hf[1] = __uint_as_float(u.x & 0xFFFF0000u);
            hf[2] = __uint_as_float(u.y << 16); hf[3] = __uint_as_float(u.y & 0xFFFF0000u);
            hf[4] = __uint_as_float(u.z << 16); hf[5] = __uint_as_float(u.z & 0xFFFF0000u);
            hf[6] = __uint_as_float(u.w << 16); hf[7] = __uint_as_float(u.w & 0xFFFF0000u);
            float p[8];
#pragma unroll
            for (int s = 0; s < 8; s++) {
                float4 qa = qx4[c8 * 17 + s * 2];
                float4 qb = qx4[c8 * 17 + s * 2 + 1];
                float v;
                v = hf[0] * qa.x;
                v = fmaf(hf[1], qa.y, v);
                v = fmaf(hf[2], qa.z, v);
                v = fmaf(hf[3], qa.w, v);
                v = fmaf(hf[4], qb.x, v);
                v = fmaf(hf[5], qb.y, v);
                v = fmaf(hf[6], qb.z, v);
                v = fmaf(hf[7], qb.w, v);
                p[s] = v;
            }
            // reduce partial dots across the 16-lane row group (DPP shuffles)
#pragma unroll
            for (int s = 0; s < 8; s++) {
                float v = p[s];
                v += __shfl_xor(v, 1);
                v += __shfl_xor(v, 2);
                v += __shfl_xor(v, 4);
                v += __shfl_xor(v, 8);
                p[s] = v + qcr[s];
            }
            float mx = p[0];
#pragma unroll
            for (int s = 1; s < 8; s++) mx = fmaxf(mx, p[s]);
            float sum = 0.f;
#pragma unroll
            for (int s = 0; s < 8; s++) { p[s] = __expf(p[s] - mx); sum += p[s]; }
            float invs = 1.0f / sum;
#pragma unroll
            for (int s = 0; s < 8; s++) {
                float a = fmaf(p[s], invs, 1e-8f);
#pragma unroll
                for (int dd = 0; dd < 8; dd++) acc[s][dd] = fmaf(a, hf[dd], acc[s][dd]);
                if (c8 == 0) dden[s] += a;
            }
        }
        if (tt < 3) {
#pragma unroll
            for (int k = 0; k < 4; k++) st[k] = stn[k];
        }
    }
    // in-wave reduce over the 4 j-lanes sharing c8 (xor 16, 32)
#pragma unroll
    for (int s = 0; s < 8; s++) {
#pragma unroll
        for (int dd = 0; dd < 8; dd++) {
            float v = acc[s][dd];
            v += __shfl_xor(v, 16);
            v += __shfl_xor(v, 32);
            acc[s][dd] = v;
        }
        float dv = dden[s];
        dv += __shfl_xor(dv, 16);
        dv += __shfl_xor(dv, 32);
        dden[s] = dv;
    }
    int wv_ = t >> 6, lane = t & 63;
    if (lane < 16) {  // leader: lane == c8
        float* vp = &vlds[wv_ * 1088 + c8 * 68];
#pragma unroll
        for (int s = 0; s < 8; s++) {
            float4 lo = {acc[s][0], acc[s][1], acc[s][2], acc[s][3]};
            float4 hi = {acc[s][4], acc[s][5], acc[s][6], acc[s][7]};
            *(float4*)&vp[s * 8] = lo;
            *(float4*)&vp[s * 8 + 4] = hi;
        }
        if (c8 == 0) {
#pragma unroll
            for (int s = 0; s < 8; s++) dlds[wv_ * 8 + s] = dden[s];
        }
    }
    __syncthreads();
#pragma unroll
    for (int rep = 0; rep < 4; rep++) {
        int o = rep * 256 + t;          // o = s*128 + d
        int s = o >> 7, d = o & 127;
        int idx = (d >> 3) * 68 + s * 8 + (d & 7);
        float v = vlds[idx] + vlds[1088 + idx] + vlds[2176 + idx] + vlds[3264 + idx];
        atomicAdd(&vec[b * 1024 + o], v);
    }
    if (t < 8) atomicAdd(&den[b * 8 + t], dlds[t] + dlds[8 + t] + dlds[16 + t] + dlds[24 + t]);
}

// ---------- K5: updates -> GRU -> MLP -> slots (+ next q) ----------

__global__ __launch_bounds__(128) void k5_update(
    const float* __restrict__ vec, const float* __restrict__ den,
    const float* __restrict__ wv, const float* __restrict__ bv,
    const float* __restrict__ wihT, const float* __restrict__ whhT,
    const float* __restrict__ bih, const float* __restrict__ bhh,
    const float* __restrict__ lnfg, const float* __restrict__ lnfb,
    const float* __restrict__ m1w, const float* __restrict__ m1b,
    const float* __restrict__ m2w, const float* __restrict__ m2b,
    float* __restrict__ slots,
    const float* __restrict__ lnsg, const float* __restrict__ lnsb,
    const float* __restrict__ wq, const float* __restrict__ bq,
    const float* __restrict__ wkT, const float* __restrict__ bk,
    float* __restrict__ qt, float* __restrict__ qc,
    float* __restrict__ out, int compute_q, int write_out) {
    __shared__ float sA[128], sB[128], sC[128];
    __shared__ float red[2];
    int bs = blockIdx.x, t = threadIdx.x;
    float dv = den[bs];
    sA[t] = vec[bs * 128 + t] / dv;
    sC[t] = slots[bs * 128 + t];
    __syncthreads();
    float upd = bv[t];
#pragma unroll 4
    for (int i = 0; i < 128; i++) upd = fmaf(sA[i], wv[i * 128 + t], upd);
    __syncthreads();
    sB[t] = upd;
    __syncthreads();
    float gi[3], gh[3];
#pragma unroll 1
    for (int gx = 0; gx < 3; gx++) {
        int g = gx * 128 + t;
        float a = bih[g], hh = bhh[g];
#pragma unroll 4
        for (int d = 0; d < 128; d++) {
            a = fmaf(sB[d], wihT[d * 384 + g], a);
            hh = fmaf(sC[d], whhT[d * 384 + g], hh);
        }
        gi[gx] = a; gh[gx] = hh;
    }
    float rg = 1.f / (1.f + expf(-(gi[0] + gh[0])));
    float zg = 1.f / (1.f + expf(-(gi[1] + gh[1])));
    float ng = tanhf(fmaf(rg, gh[2], gi[2]));
    float hnew = (1.f - zg) * ng + zg * sC[t];
    float m = block128_sum(hnew, red) * (1.0f / 128.0f);
    float e = hnew - m;
    float var = block128_sum(e * e, red) * (1.0f / 128.0f);
    float inv = rsqrtf(var + 1e-5f);
    __syncthreads();
    sA[t] = fmaf(e * inv, lnfg[t], lnfb[t]);
    __syncthreads();
    float m1 = m1b[t];
#pragma unroll 4
    for (int i = 0; i < 128; i++) m1 = fmaf(sA[i], m1w[i * 128 + t], m1);
    __syncthreads();
    sB[t] = m1;
    __syncthreads();
    float m2 = m2b[t];
#pragma unroll 4
    for (int i = 0; i < 128; i++) m2 = fmaf(sB[i], m2w[i * 128 + t], m2);
    float snew = hnew + m2;
    slots[bs * 128 + t] = snew;
    if (write_out) out[bs * 128 + t] = snew;
    if (compute_q) {
        emit_q(snew, bs, lnsg, lnsb, wq, bq, wkT, bk, qt, qc,
               const_cast<float*>(vec), const_cast<float*>(den), sA, red);
    }
}

// ---------- launch ----------

extern "C" void kernel_launch(void* const* d_in, const int* in_sizes, int n_in,
                              void* d_out, int out_size, void* d_ws, size_t ws_size,
                              hipStream_t stream) {
    const float* inputs = (const float*)d_in[0];
    const float* embed  = (const float*)d_in[1];
    const float* mu     = (const float*)d_in[2];
    const float* sg     = (const float*)d_in[3];
    const float* w0 = (const float*)d_in[4];  const float* b0 = (const float*)d_in[5];
    const float* w1 = (const float*)d_in[6];  const float* b1 = (const float*)d_in[7];
    const float* w2 = (const float*)d_in[8];  const float* b2 = (const float*)d_in[9];
    const float* w3 = (const float*)d_in[10]; const float* b3 = (const float*)d_in[11];
    const float* w4 = (const float*)d_in[12]; const float* b4 = (const float*)d_in[13];
    const float* w5 = (const float*)d_in[14]; const float* b5 = (const float*)d_in[15];
    const float* w7 = (const float*)d_in[16]; const float* b7 = (const float*)d_in[17];
    const float* wq = (const float*)d_in[18]; const float* bq = (const float*)d_in[19];
    const float* wk = (const float*)d_in[20]; const float* bk = (const float*)d_in[21];
    const float* wv = (const float*)d_in[22]; const float* bv = (const float*)d_in[23];
    const float* ln_in_g = (const float*)d_in[24]; const float* ln_in_b = (const float*)d_in[25];
    const float* ln_sl_g = (const float*)d_in[26]; const float* ln_sl_b = (const float*)d_in[27];
    const float* ln_ff_g = (const float*)d_in[28]; const float* ln_ff_b = (const float*)d_in[29];
    const float* gwih = (const float*)d_in[30]; const float* gwhh = (const float*)d_in[31];
    const float* gbih = (const float*)d_in[32]; const float* gbhh = (const float*)d_in[33];
    const float* m1w = (const float*)d_in[34]; const float* m1b = (const float*)d_in[35];
    const float* m2w = (const float*)d_in[36]; const float* m2b = (const float*)d_in[37];

    char* ws = (char*)d_ws;
    uint2* hlnb = (uint2*)ws;
    size_t off = (size_t)NB_ * 128 * 2;  // 64 MB bf16 hln row-major
    float* Wh    = (float*)(ws + off); off += 66 * 128 * 4;
    float* bh    = (float*)(ws + off); off += 128 * 4;
    float* slots = (float*)(ws + off); off += 64 * 128 * 4;
    float* qt    = (float*)(ws + off); off += 64 * 128 * 4;
    float* qc    = (float*)(ws + off); off += 64 * 4;
    float* vec   = (float*)(ws + off); off += 64 * 128 * 4;
    float* den   = (float*)(ws + off); off += 64 * 4;
    float* wihT  = (float*)(ws + off); off += 384 * 128 * 4;
    float* whhT  = (float*)(ws + off); off += 384 * 128 * 4;
    float* wkT   = (float*)(ws + off); off += 128 * 128 * 4;

    k0_transpose<<<448, 256, 0, stream>>>(gwih, gwhh, wk, wihT, whhT, wkT);
    k1_setup<<<1, 256, 0, stream>>>(w0, b0, w1, b1, w2, b2, w3, b3, w4, b4, w5, b5,
                                    w7, b7, mu, sg, Wh, bh, slots);
    k2_hln<<<NB_ / 128, 256, 0, stream>>>(inputs, embed, Wh, bh, ln_in_g, ln_in_b, hlnb);
    k3_q<<<64, 128, 0, stream>>>(slots, ln_sl_g, ln_sl_b, wq, bq, wkT, bk, qt, qc, vec, den);
    for (int it = 0; it < 3; it++) {
        k4_attn<<<1024, 256, 0, stream>>>((const uint4*)hlnb, qt, qc, vec, den);
        k5_update<<<64, 128, 0, stream>>>(vec, den, wv, bv, wihT, whhT, gbih, gbhh,
                                          ln_ff_g, ln_ff_b, m1w, m1b, m2w, m2b, slots,
                                          ln_sl_g, ln_sl_b, wq, bq, wkT, bk, qt, qc,
                                          (float*)d_out, (it < 2) ? 1 : 0, (it == 2) ? 1 : 0);
    }
}

// Round 10
// 448.511 us; speedup vs baseline: 1.2240x; 1.2240x over previous
//
#include <hip/hip_runtime.h>

// SlotAttention fused implementation (bf16 hln, dual layout, MFMA attention).
//   - 6-layer linear stack folded into effective 66->128 affine (Wh, bh).
//   - k,v projections folded out of the N dimension:
//       q.k_n = (wk@q) . hln_n + q.bk ;  updates = (sum attn*hln)/den @ wv + bv
//   - hln materialized bf16 in BOTH layouts: row-major [NB][128] (phase-1 A)
//     and transposed [128][NB] (phase-2 B). 128 MB total, L3-resident.
//   - slot init: JAX partitionable threefry: bits[i] = o0^o1, counter (0,i).
//   - k4: per-wave 64-row tile; phase1 D=H.Q^T via mfma_16x16x32_bf16 (q in
//     regs), shfl softmax, phase2 U=attn^T.H via MFMA (attn via 1KB LDS).

#define B_  8
#define N_  32768
#define NB_ (B_ * N_)   // 262144 rows
#define D_  128
#define S_  8

typedef unsigned int u32;
typedef unsigned short u16;
typedef __attribute__((ext_vector_type(8))) short bf16x8;
typedef __attribute__((ext_vector_type(4))) float f32x4;

__device__ inline u32 bfr1(float x) {  // f32 -> bf16 (RNE)
    u32 u = __float_as_uint(x);
    return (u + 0x7FFFu + ((u >> 16) & 1u)) >> 16;
}
__device__ inline u32 bfpack2(u32 lo, u32 hi) { return lo | (hi << 16); }

// threefry2x32, key = (0, 42)  (jax.random.key(42))
__device__ inline void threefry42(u32 c0, u32 c1, u32& o0, u32& o1) {
    const u32 k0 = 0u, k1 = 42u, k2 = 0x1BD11BDAu ^ 0u ^ 42u;
    const u32 ks[3] = {k0, k1, k2};
    u32 x0 = c0 + k0, x1 = c1 + k1;
    const int rA[4] = {13, 15, 26, 6}, rB[4] = {17, 29, 16, 24};
#pragma unroll
    for (int i = 0; i < 5; i++) {
#pragma unroll
        for (int k = 0; k < 4; k++) {
            int r = (i & 1) ? rB[k] : rA[k];
            x0 += x1;
            x1 = (x1 << r) | (x1 >> (32 - r));
            x1 ^= x0;
        }
        x0 += ks[(i + 1) % 3];
        x1 += ks[(i + 2) % 3] + (u32)(i + 1);
    }
    o0 = x0; o1 = x1;
}

// jax uniform(-0.99999994, 1) -> sqrt(2)*erfinv  (XLA ErfInv32 polynomial)
__device__ inline float bits_to_normal(u32 b) {
    float f = __uint_as_float((b >> 9) | 0x3f800000u) - 1.0f;  // [0,1)
    const float lo = -0.99999994f;
    float r = fmaxf(lo, f * 1.99999994f + lo);
    float w = -log1pf(-r * r);
    float p;
    if (w < 5.0f) {
        w -= 2.5f;
        p = 2.81022636e-08f;
        p = fmaf(p, w, 3.43273939e-07f);
        p = fmaf(p, w, -3.5233877e-06f);
        p = fmaf(p, w, -4.39150654e-06f);
        p = fmaf(p, w, 0.00021858087f);
        p = fmaf(p, w, -0.00125372503f);
        p = fmaf(p, w, -0.00417768164f);
        p = fmaf(p, w, 0.246640727f);
        p = fmaf(p, w, 1.50140941f);
    } else {
        w = sqrtf(w) - 3.0f;
        p = -0.000200214257f;
        p = fmaf(p, w, 0.000100950558f);
        p = fmaf(p, w, 0.00134934322f);
        p = fmaf(p, w, -0.00367342844f);
        p = fmaf(p, w, 0.00573950773f);
        p = fmaf(p, w, -0.0076224613f);
        p = fmaf(p, w, 0.00943887047f);
        p = fmaf(p, w, 1.00167406f);
        p = fmaf(p, w, 2.83297682f);
    }
    return 1.41421356f * (p * r);
}

// 128-thread block sum (2 waves), red = 2-float shared scratch
__device__ inline float block128_sum(float v, float* red) {
#pragma unroll
    for (int o = 32; o; o >>= 1) v += __shfl_down(v, o);
    __syncthreads();
    if ((threadIdx.x & 63) == 0) red[threadIdx.x >> 6] = v;
    __syncthreads();
    return red[0] + red[1];
}

// LN(slot row) -> q -> qtilde(scaled), qc(scaled); zero vec/den accumulators.
__device__ void emit_q(float x, int bs,
                       const float* lnsg, const float* lnsb,
                       const float* wq, const float* bq,
                       const float* wkT, const float* bk,
                       float* qt, float* qc, float* vec, float* den,
                       float* shA, float* red) {
    int t = threadIdx.x;
    float m = block128_sum(x, red) * (1.0f / 128.0f);
    float e = x - m;
    float var = block128_sum(e * e, red) * (1.0f / 128.0f);
    float inv = rsqrtf(var + 1e-5f);
    __syncthreads();
    shA[t] = fmaf(e * inv, lnsg[t], lnsb[t]);
    __syncthreads();
    float q = bq[t];
#pragma unroll 4
    for (int i = 0; i < 128; i++) q = fmaf(shA[i], wq[i * 128 + t], q);
    __syncthreads();
    shA[t] = q;
    __syncthreads();
    float a2 = 0.f;
#pragma unroll 4
    for (int j = 0; j < 128; j++) a2 = fmaf(wkT[j * 128 + t], shA[j], a2);
    const float scale = 0.08838834764831845f;  // 128^-0.5
    qt[bs * 128 + t] = a2 * scale;
    float pr = block128_sum(shA[t] * bk[t], red);
    if (t == 0) { qc[bs] = pr * scale; den[bs] = 0.f; }
    vec[bs * 128 + t] = 0.f;
}

// ---------- K0: transpose gru weights + wk for coalesced access ----------

__global__ __launch_bounds__(256) void k0_transpose(
    const float* __restrict__ wih, const float* __restrict__ whh,
    const float* __restrict__ wk,
    float* __restrict__ wihT, float* __restrict__ whhT, float* __restrict__ wkT) {
    int idx = blockIdx.x * 256 + threadIdx.x;
    if (idx < 49152) {
        int d = idx / 384, g = idx % 384;
        wihT[idx] = wih[g * 128 + d];
    } else if (idx < 98304) {
        int o = idx - 49152;
        int d = o / 384, g = o % 384;
        whhT[o] = whh[g * 128 + d];
    } else if (idx < 114688) {
        int o = idx - 98304;
        int j = o >> 7, tcol = o & 127;
        wkT[o] = wk[tcol * 128 + j];
    }
}

// ---------- K1: fold weights, init slots ----------

__global__ __launch_bounds__(256) void k1_setup(
    const float* __restrict__ w0, const float* __restrict__ b0,
    const float* __restrict__ w1, const float* __restrict__ b1,
    const float* __restrict__ w2, const float* __restrict__ b2,
    const float* __restrict__ w3, const float* __restrict__ b3,
    const float* __restrict__ w4, const float* __restrict__ b4,
    const float* __restrict__ w5, const float* __restrict__ b5,
    const float* __restrict__ w7, const float* __restrict__ b7,
    const float* __restrict__ mu, const float* __restrict__ sg,
    float* __restrict__ Wh, float* __restrict__ bh, float* __restrict__ slots) {
    __shared__ float A[192], Bt[96], bb[64], bb2[32];
    __shared__ float stats[2];
    int t = threadIdx.x;
    for (int i = t; i < 192; i += 256) A[i] = w0[i];
    for (int i = t; i < 64; i += 256) bb[i] = b0[i];
    __syncthreads();
    const float* wl[5] = {w1, w2, w3, w4, w5};
    const float* bl[5] = {b1, b2, b3, b4, b5};
    int kin = 64;
    for (int l = 0; l < 5; l++) {
        const float* w = wl[l];
        const float* bias = bl[l];
        if (t < 96) {
            int i = t / 32, j = t % 32;
            float acc = 0.f;
            for (int k = 0; k < kin; k++) acc += A[i * kin + k] * w[k * 32 + j];
            Bt[i * 32 + j] = acc;
        } else if (t < 128) {
            int j = t - 96;
            float acc = bias[j];
            for (int k = 0; k < kin; k++) acc += bb[k] * w[k * 32 + j];
            bb2[j] = acc;
        }
        __syncthreads();
        if (t < 96) A[t] = Bt[t];
        if (t < 32) bb[t] = bb2[t];
        __syncthreads();
        kin = 32;
    }
    for (int idx = t; idx < 66 * 128; idx += 256) {
        int i = idx >> 7, j = idx & 127;
        float acc = w7[idx];
        if (i < 3) {
            for (int k = 0; k < 32; k++) acc += A[i * 32 + k] * w7[(66 + k) * 128 + j];
        }
        Wh[idx] = acc;
    }
    for (int j = t; j < 128; j += 256) {
        float acc = b7[j];
        for (int k = 0; k < 32; k++) acc += bb[k] * w7[(66 + k) * 128 + j];
        bh[j] = acc;
    }
    if (t == 0) {
        float s1 = 0.f, s2 = 0.f;
        for (int d = 0; d < 128; d++) { s1 += mu[d]; s2 += sg[d]; }
        float mmu = s1 / 128.f, msg = s2 / 128.f;
        float ss = 0.f;
        for (int d = 0; d < 128; d++) { float e = sg[d] - msg; ss += e * e; }
        stats[0] = mmu;
        stats[1] = sqrtf(64.f * ss / 8191.f);  // std over broadcast 8192, ddof=1
    }
    __syncthreads();
    float mean = stats[0], sd = stats[1];
    for (int p = t; p < 8192; p += 256) {
        u32 o0, o1;
        threefry42(0u, (u32)p, o0, o1);
        slots[p] = fmaf(sd, bits_to_normal(o0 ^ o1), mean);
    }
}

// ---------- K2: build hln bf16, row-major AND transposed ----------
// 128 rows/block; thread (tr 0-15, tc 0-15): rows tr*8..+7, f4-col quads {tc, tc+16}.

__global__ __launch_bounds__(256) void k2_hln(
    const float* __restrict__ inputs, const float* __restrict__ embed,
    const float* __restrict__ Wh, const float* __restrict__ bh,
    const float* __restrict__ g, const float* __restrict__ bbias,
    uint2* __restrict__ hlnb, u16* __restrict__ hlnT) {
    __shared__ __align__(16) float Whs[66 * 132];   // 34848 B (stride 33 f4)
    __shared__ __align__(16) float ebuf[128 * 68];  // 34816 B (stride 17 f4)
    __shared__ __align__(16) float bhs[128], gs[128], bs_[128];
    int t = threadIdx.x;
    for (int gi = t; gi < 66 * 128; gi += 256) {
        int i = gi >> 7, d = gi & 127;
        Whs[i * 132 + d] = Wh[gi];
    }
    if (t < 128) { bhs[t] = bh[t]; gs[t] = g[t]; bs_[t] = bbias[t]; }
    size_t rbase = (size_t)blockIdx.x * 128;
    for (int idx = t; idx < 384; idx += 256)
        ebuf[(idx / 3) * 68 + (idx % 3)] = inputs[rbase * 3 + idx];
    for (int idx = t; idx < 128 * 63; idx += 256) {
        int rr = idx / 63, i = idx - rr * 63;
        ebuf[rr * 68 + 3 + i] = embed[rbase * 63 + idx];
    }
    __syncthreads();
    int tr = t >> 4, tc = t & 15;
    const float4* Whs4 = (const float4*)Whs;
    const float4* ebuf4 = (const float4*)ebuf;
    float4 acc0[8], acc1[8];
    float4 b40 = *(const float4*)&bhs[tc * 4];
    float4 b41 = *(const float4*)&bhs[64 + tc * 4];
#pragma unroll
    for (int r8 = 0; r8 < 8; r8++) { acc0[r8] = b40; acc1[r8] = b41; }
#pragma unroll 2
    for (int kc = 0; kc < 16; kc++) {
        float4 e4[8];
#pragma unroll
        for (int r8 = 0; r8 < 8; r8++) e4[r8] = ebuf4[(tr * 8 + r8) * 17 + kc];
#pragma unroll
        for (int kk = 0; kk < 4; kk++) {
            float4 w0t = Whs4[(kc * 4 + kk) * 33 + tc];
            float4 w1t = Whs4[(kc * 4 + kk) * 33 + 16 + tc];
#pragma unroll
            for (int r8 = 0; r8 < 8; r8++) {
                float e = (kk == 0) ? e4[r8].x : (kk == 1) ? e4[r8].y
                        : (kk == 2) ? e4[r8].z : e4[r8].w;
                acc0[r8].x = fmaf(e, w0t.x, acc0[r8].x);
                acc0[r8].y = fmaf(e, w0t.y, acc0[r8].y);
                acc0[r8].z = fmaf(e, w0t.z, acc0[r8].z);
                acc0[r8].w = fmaf(e, w0t.w, acc0[r8].w);
                acc1[r8].x = fmaf(e, w1t.x, acc1[r8].x);
                acc1[r8].y = fmaf(e, w1t.y, acc1[r8].y);
                acc1[r8].z = fmaf(e, w1t.z, acc1[r8].z);
                acc1[r8].w = fmaf(e, w1t.w, acc1[r8].w);
            }
        }
    }
    // tail k = 64, 65
#pragma unroll
    for (int k = 64; k < 66; k++) {
        float4 w0t = Whs4[k * 33 + tc];
        float4 w1t = Whs4[k * 33 + 16 + tc];
#pragma unroll
        for (int r8 = 0; r8 < 8; r8++) {
            float e = ebuf[(tr * 8 + r8) * 68 + k];
            acc0[r8].x = fmaf(e, w0t.x, acc0[r8].x); acc0[r8].y = fmaf(e, w0t.y, acc0[r8].y);
            acc0[r8].z = fmaf(e, w0t.z, acc0[r8].z); acc0[r8].w = fmaf(e, w0t.w, acc0[r8].w);
            acc1[r8].x = fmaf(e, w1t.x, acc1[r8].x); acc1[r8].y = fmaf(e, w1t.y, acc1[r8].y);
            acc1[r8].z = fmaf(e, w1t.z, acc1[r8].z); acc1[r8].w = fmaf(e, w1t.w, acc1[r8].w);
        }
    }
    // per-row LN across the 16 tc lanes; write row-major + transposed
    float4 gg0 = *(const float4*)&gs[tc * 4];
    float4 gg1 = *(const float4*)&gs[64 + tc * 4];
    float4 bb0 = *(const float4*)&bs_[tc * 4];
    float4 bb1 = *(const float4*)&bs_[64 + tc * 4];
    u32 colw[8][4];
#pragma unroll
    for (int r8 = 0; r8 < 8; r8++) {
        float v = acc0[r8].x + acc0[r8].y + acc0[r8].z + acc0[r8].w
                + acc1[r8].x + acc1[r8].y + acc1[r8].z + acc1[r8].w;
        v += __shfl_xor(v, 1); v += __shfl_xor(v, 2);
        v += __shfl_xor(v, 4); v += __shfl_xor(v, 8);
        float m = v * (1.0f / 128.0f);
        float e0x = acc0[r8].x - m, e0y = acc0[r8].y - m, e0z = acc0[r8].z - m, e0w = acc0[r8].w - m;
        float e1x = acc1[r8].x - m, e1y = acc1[r8].y - m, e1z = acc1[r8].z - m, e1w = acc1[r8].w - m;
        float s2 = e0x * e0x + e0y * e0y + e0z * e0z + e0w * e0w
                 + e1x * e1x + e1y * e1y + e1z * e1z + e1w * e1w;
        s2 += __shfl_xor(s2, 1); s2 += __shfl_xor(s2, 2);
        s2 += __shfl_xor(s2, 4); s2 += __shfl_xor(s2, 8);
        float inv = rsqrtf(s2 * (1.0f / 128.0f) + 1e-5f);
        u32 b0 = bfr1(fmaf(e0x * inv, gg0.x, bb0.x));
        u32 b1 = bfr1(fmaf(e0y * inv, gg0.y, bb0.y));
        u32 b2 = bfr1(fmaf(e0z * inv, gg0.z, bb0.z));
        u32 b3 = bfr1(fmaf(e0w * inv, gg0.w, bb0.w));
        u32 b4 = bfr1(fmaf(e1x * inv, gg1.x, bb1.x));
        u32 b5 = bfr1(fmaf(e1y * inv, gg1.y, bb1.y));
        u32 b6 = bfr1(fmaf(e1z * inv, gg1.z, bb1.z));
        u32 b7 = bfr1(fmaf(e1w * inv, gg1.w, bb1.w));
        size_t row = rbase + tr * 8 + r8;
        uint2 o0; o0.x = bfpack2(b0, b1); o0.y = bfpack2(b2, b3);
        uint2 o1; o1.x = bfpack2(b4, b5); o1.y = bfpack2(b6, b7);
        hlnb[row * 32 + tc] = o0;
        hlnb[row * 32 + 16 + tc] = o1;
        int hw = r8 >> 1;
        if (r8 & 1) {
            colw[0][hw] |= b0 << 16; colw[1][hw] |= b1 << 16;
            colw[2][hw] |= b2 << 16; colw[3][hw] |= b3 << 16;
            colw[4][hw] |= b4 << 16; colw[5][hw] |= b5 << 16;
            colw[6][hw] |= b6 << 16; colw[7][hw] |= b7 << 16;
        } else {
            colw[0][hw] = b0; colw[1][hw] = b1; colw[2][hw] = b2; colw[3][hw] = b3;
            colw[4][hw] = b4; colw[5][hw] = b5; colw[6][hw] = b6; colw[7][hw] = b7;
        }
    }
    size_t rb = rbase + tr * 8;
#pragma unroll
    for (int di = 0; di < 8; di++) {
        int dg = (di < 4) ? (tc * 4 + di) : (64 + tc * 4 + (di - 4));
        uint4 ov; ov.x = colw[di][0]; ov.y = colw[di][1];
        ov.z = colw[di][2]; ov.w = colw[di][3];
        *(uint4*)(hlnT + (size_t)dg * NB_ + rb) = ov;
    }
}

// ---------- K3: initial q from slots ----------

__global__ __launch_bounds__(128) void k3_q(
    const float* __restrict__ slots,
    const float* __restrict__ lnsg, const float* __restrict__ lnsb,
    const float* __restrict__ wq, const float* __restrict__ bq,
    const float* __restrict__ wkT, const float* __restrict__ bk,
    float* __restrict__ qt, float* __restrict__ qc,
    float* __restrict__ vec, float* __restrict__ den) {
    __shared__ float shA[128];
    __shared__ float red[2];
    int bs = blockIdx.x;
    float x = slots[bs * 128 + threadIdx.x];
    emit_q(x, bs, lnsg, lnsb, wq, bq, wkT, bk, qt, qc, vec, den, shA, red);
}

// ---------- K4: MFMA attention pass ----------
// 1024 blocks x 4 waves; wave owns a private 64-row tile.
// Phase1: D[64x16] = H.Q^T (A = hln rows from global, B = q regs, 16 MFMA).
// Softmax via shfl over the 8 slot-lanes. Phase2: U[16x128] = attn^T.H
// (A = bf16 attn from LDS, B = hlnT from global, 16 MFMA).

__global__ __launch_bounds__(256) void k4_attn(
    const uint4* __restrict__ hlnb4, const u16* __restrict__ hlnT,
    const float* __restrict__ qt, const float* __restrict__ qc,
    float* __restrict__ vec, float* __restrict__ den) {
    __shared__ __align__(16) u16 attn_lds[4][8 * 72];  // per-wave, padded
    __shared__ __align__(16) float vlds[4][1024];
    __shared__ float dlds[4][8];
    int t = threadIdx.x;
    int w = t >> 6, l = t & 63;
    int blk = blockIdx.x;
    int b = blk >> 7, slab = blk & 127;
    size_t row0 = (size_t)b * N_ + (size_t)slab * 256 + (size_t)w * 64;
    int c16 = l & 15, g = l >> 4;

    // B-frags for phase 1: q in bf16, loop-invariant (slot = c16, k-chunks).
    bf16x8 qf[4];
#pragma unroll
    for (int kc = 0; kc < 4; kc++) {
        uint4 qu = {0u, 0u, 0u, 0u};
        if (c16 < 8) {
            const float* qp = qt + b * 1024 + c16 * 128 + kc * 32 + g * 8;
            float4 qa = *(const float4*)qp;
            float4 qb = *(const float4*)(qp + 4);
            qu.x = bfpack2(bfr1(qa.x), bfr1(qa.y));
            qu.y = bfpack2(bfr1(qa.z), bfr1(qa.w));
            qu.z = bfpack2(bfr1(qb.x), bfr1(qb.y));
            qu.w = bfpack2(bfr1(qb.z), bfr1(qb.w));
        }
        qf[kc] = *(bf16x8*)&qu;
    }
    float qcv = (c16 < 8) ? qc[b * 8 + c16] : 0.f;

    // ---- phase 1: 16 MFMA ----
    f32x4 dacc[4];
#pragma unroll
    for (int mt = 0; mt < 4; mt++) dacc[mt] = (f32x4){0.f, 0.f, 0.f, 0.f};
#pragma unroll
    for (int mt = 0; mt < 4; mt++) {
        uint4 au0 = hlnb4[(row0 + mt * 16 + c16) * 16 + 0 + g];
        uint4 au1 = hlnb4[(row0 + mt * 16 + c16) * 16 + 4 + g];
        uint4 au2 = hlnb4[(row0 + mt * 16 + c16) * 16 + 8 + g];
        uint4 au3 = hlnb4[(row0 + mt * 16 + c16) * 16 + 12 + g];
        dacc[mt] = __builtin_amdgcn_mfma_f32_16x16x32_bf16(*(bf16x8*)&au0, qf[0], dacc[mt], 0, 0, 0);
        dacc[mt] = __builtin_amdgcn_mfma_f32_16x16x32_bf16(*(bf16x8*)&au1, qf[1], dacc[mt], 0, 0, 0);
        dacc[mt] = __builtin_amdgcn_mfma_f32_16x16x32_bf16(*(bf16x8*)&au2, qf[2], dacc[mt], 0, 0, 0);
        dacc[mt] = __builtin_amdgcn_mfma_f32_16x16x32_bf16(*(bf16x8*)&au3, qf[3], dacc[mt], 0, 0, 0);
    }

    // ---- softmax over slots (lane dim c16, masks 1/2/4) + attn to LDS ----
    float denacc = 0.f;
#pragma unroll
    for (int mt = 0; mt < 4; mt++) {
        float pv[4];
#pragma unroll
        for (int r = 0; r < 4; r++) {
            float v = dacc[mt][r] + qcv;
            float mx = v;
            mx = fmaxf(mx, __shfl_xor(mx, 1));
            mx = fmaxf(mx, __shfl_xor(mx, 2));
            mx = fmaxf(mx, __shfl_xor(mx, 4));
            float e = __expf(v - mx);
            float ssum = e;
            ssum += __shfl_xor(ssum, 1);
            ssum += __shfl_xor(ssum, 2);
            ssum += __shfl_xor(ssum, 4);
            float a = fmaf(e, 1.0f / ssum, 1e-8f);
            pv[r] = a;
            denacc += a;
        }
        if (c16 < 8) {
            uint2 pw;
            pw.x = bfpack2(bfr1(pv[0]), bfr1(pv[1]));
            pw.y = bfpack2(bfr1(pv[2]), bfr1(pv[3]));
            *(uint2*)&attn_lds[w][c16 * 72 + mt * 16 + g * 4] = pw;
        }
    }
    denacc += __shfl_xor(denacc, 16);
    denacc += __shfl_xor(denacc, 32);
    if (l < 8) dlds[w][l] = denacc;

    // ---- phase 2: U[16x128] = attn^T[16x64] . H[64x128], 16 MFMA ----
    f32x4 uacc[8];
#pragma unroll
    for (int nt = 0; nt < 8; nt++) uacc[nt] = (f32x4){0.f, 0.f, 0.f, 0.f};
#pragma unroll
    for (int kr = 0; kr < 2; kr++) {
        uint4 afu = *(const uint4*)&attn_lds[w][c16 * 72 + kr * 32 + g * 8];
        bf16x8 af = *(bf16x8*)&afu;
#pragma unroll
        for (int nt = 0; nt < 8; nt++) {
            const u16* bp = hlnT + (size_t)(nt * 16 + c16) * NB_ + row0 + kr * 32 + g * 8;
            uint4 bu = *(const uint4*)bp;
            uacc[nt] = __builtin_amdgcn_mfma_f32_16x16x32_bf16(af, *(bf16x8*)&bu, uacc[nt], 0, 0, 0);
        }
    }
    // lane holds U[slot = g*4+r][d = nt*16 + c16]; slots valid for g < 2
    if (g < 2) {
#pragma unroll
        for (int nt = 0; nt < 8; nt++) {
#pragma unroll
            for (int r = 0; r < 4; r++) {
                vlds[w][(g * 4 + r) * 128 + nt * 16 + c16] = uacc[nt][r];
            }
        }
    }
    __syncthreads();
#pragma unroll
    for (int rep = 0; rep < 4; rep++) {
        int o = rep * 256 + t;
        float v = vlds[0][o] + vlds[1][o] + vlds[2][o] + vlds[3][o];
        atomicAdd(&vec[b * 1024 + o], v);
    }
    if (t < 8) atomicAdd(&den[b * 8 + t], dlds[0][t] + dlds[1][t] + dlds[2][t] + dlds[3][t]);
}

// ---------- K5: updates -> GRU -> MLP -> slots (+ next q) ----------

__global__ __launch_bounds__(128) void k5_update(
    const float* __restrict__ vec, const float* __restrict__ den,
    const float* __restrict__ wv, const float* __restrict__ bv,
    const float* __restrict__ wihT, const float* __restrict__ whhT,
    const float* __restrict__ bih, const float* __restrict__ bhh,
    const float* __restrict__ lnfg, const float* __restrict__ lnfb,
    const float* __restrict__ m1w, const float* __restrict__ m1b,
    const float* __restrict__ m2w, const float* __restrict__ m2b,
    float* __restrict__ slots,
    const float* __restrict__ lnsg, const float* __restrict__ lnsb,
    const float* __restrict__ wq, const float* __restrict__ bq,
    const float* __restrict__ wkT, const float* __restrict__ bk,
    float* __restrict__ qt, float* __restrict__ qc,
    float* __restrict__ out, int compute_q, int write_out) {
    __shared__ float sA[128], sB[128], sC[128];
    __shared__ float red[2];
    int bs = blockIdx.x, t = threadIdx.x;
    float dv = den[bs];
    sA[t] = vec[bs * 128 + t] / dv;
    sC[t] = slots[bs * 128 + t];
    __syncthreads();
    float upd = bv[t];
#pragma unroll 4
    for (int i = 0; i < 128; i++) upd = fmaf(sA[i], wv[i * 128 + t], upd);
    __syncthreads();
    sB[t] = upd;
    __syncthreads();
    float gi[3], gh[3];
#pragma unroll 1
    for (int gx = 0; gx < 3; gx++) {
        int g = gx * 128 + t;
        float a = bih[g], hh = bhh[g];
#pragma unroll 4
        for (int d = 0; d < 128; d++) {
            a = fmaf(sB[d], wihT[d * 384 + g], a);
            hh = fmaf(sC[d], whhT[d * 384 + g], hh);
        }
        gi[gx] = a; gh[gx] = hh;
    }
    float rg = 1.f / (1.f + expf(-(gi[0] + gh[0])));
    float zg = 1.f / (1.f + expf(-(gi[1] + gh[1])));
    float ng = tanhf(fmaf(rg, gh[2], gi[2]));
    float hnew = (1.f - zg) * ng + zg * sC[t];
    float m = block128_sum(hnew, red) * (1.0f / 128.0f);
    float e = hnew - m;
    float var = block128_sum(e * e, red) * (1.0f / 128.0f);
    float inv = rsqrtf(var + 1e-5f);
    __syncthreads();
    sA[t] = fmaf(e * inv, lnfg[t], lnfb[t]);
    __syncthreads();
    float m1 = m1b[t];
#pragma unroll 4
    for (int i = 0; i < 128; i++) m1 = fmaf(sA[i], m1w[i * 128 + t], m1);
    __syncthreads();
    sB[t] = m1;
    __syncthreads();
    float m2 = m2b[t];
#pragma unroll 4
    for (int i = 0; i < 128; i++) m2 = fmaf(sB[i], m2w[i * 128 + t], m2);
    float snew = hnew + m2;
    slots[bs * 128 + t] = snew;
    if (write_out) out[bs * 128 + t] = snew;
    if (compute_q) {
        emit_q(snew, bs, lnsg, lnsb, wq, bq, wkT, bk, qt, qc,
               const_cast<float*>(vec), const_cast<float*>(den), sA, red);
    }
}

// ---------- launch ----------

extern "C" void kernel_launch(void* const* d_in, const int* in_sizes, int n_in,
                              void* d_out, int out_size, void* d_ws, size_t ws_size,
                              hipStream_t stream) {
    const float* inputs = (const float*)d_in[0];
    const float* embed  = (const float*)d_in[1];
    const float* mu     = (const float*)d_in[2];
    const float* sg     = (const float*)d_in[3];
    const float* w0 = (const float*)d_in[4];  const float* b0 = (const float*)d_in[5];
    const float* w1 = (const float*)d_in[6];  const float* b1 = (const float*)d_in[7];
    const float* w2 = (const float*)d_in[8];  const float* b2 = (const float*)d_in[9];
    const float* w3 = (const float*)d_in[10]; const float* b3 = (const float*)d_in[11];
    const float* w4 = (const float*)d_in[12]; const float* b4 = (const float*)d_in[13];
    const float* w5 = (const float*)d_in[14]; const float* b5 = (const float*)d_in[15];
    const float* w7 = (const float*)d_in[16]; const float* b7 = (const float*)d_in[17];
    const float* wq = (const float*)d_in[18]; const float* bq = (const float*)d_in[19];
    const float* wk = (const float*)d_in[20]; const float* bk = (const float*)d_in[21];
    const float* wv = (const float*)d_in[22]; const float* bv = (const float*)d_in[23];
    const float* ln_in_g = (const float*)d_in[24]; const float* ln_in_b = (const float*)d_in[25];
    const float* ln_sl_g = (const float*)d_in[26]; const float* ln_sl_b = (const float*)d_in[27];
    const float* ln_ff_g = (const float*)d_in[28]; const float* ln_ff_b = (const float*)d_in[29];
    const float* gwih = (const float*)d_in[30]; const float* gwhh = (const float*)d_in[31];
    const float* gbih = (const float*)d_in[32]; const float* gbhh = (const float*)d_in[33];
    const float* m1w = (const float*)d_in[34]; const float* m1b = (const float*)d_in[35];
    const float* m2w = (const float*)d_in[36]; const float* m2b = (const float*)d_in[37];

    char* ws = (char*)d_ws;
    uint2* hlnb = (uint2*)ws;
    size_t off = (size_t)NB_ * 128 * 2;  // 64 MB bf16 hln row-major
    u16* hlnT = (u16*)(ws + off); off += (size_t)NB_ * 128 * 2;  // 64 MB transposed
    float* Wh    = (float*)(ws + off); off += 66 * 128 * 4;
    float* bh    = (float*)(ws + off); off += 128 * 4;
    float* slots = (float*)(ws + off); off += 64 * 128 * 4;
    float* qt    = (float*)(ws + off); off += 64 * 128 * 4;
    float* qc    = (float*)(ws + off); off += 64 * 4;
    float* vec   = (float*)(ws + off); off += 64 * 128 * 4;
    float* den   = (float*)(ws + off); off += 64 * 4;
    float* wihT  = (float*)(ws + off); off += 384 * 128 * 4;
    float* whhT  = (float*)(ws + off); off += 384 * 128 * 4;
    float* wkT   = (float*)(ws + off); off += 128 * 128 * 4;

    k0_transpose<<<448, 256, 0, stream>>>(gwih, gwhh, wk, wihT, whhT, wkT);
    k1_setup<<<1, 256, 0, stream>>>(w0, b0, w1, b1, w2, b2, w3, b3, w4, b4, w5, b5,
                                    w7, b7, mu, sg, Wh, bh, slots);
    k2_hln<<<NB_ / 128, 256, 0, stream>>>(inputs, embed, Wh, bh, ln_in_g, ln_in_b,
                                          hlnb, hlnT);
    k3_q<<<64, 128, 0, stream>>>(slots, ln_sl_g, ln_sl_b, wq, bq, wkT, bk, qt, qc, vec, den);
    for (int it = 0; it < 3; it++) {
        k4_attn<<<1024, 256, 0, stream>>>((const uint4*)hlnb, hlnT, qt, qc, vec, den);
        k5_update<<<64, 128, 0, stream>>>(vec, den, wv, bv, wihT, whhT, gbih, gbhh,
                                          ln_ff_g, ln_ff_b, m1w, m1b, m2w, m2b, slots,
                                          ln_sl_g, ln_sl_b, wq, bq, wkT, bk, qt, qc,
                                          (float*)d_out, (it < 2) ? 1 : 0, (it == 2) ? 1 : 0);
    }
}